// Round 4
// baseline (536.033 us; speedup 1.0000x reference)
//
#include <hip/hip_runtime.h>
#include <hip/hip_bf16.h>

typedef __hip_bfloat16 bf16;
typedef __attribute__((ext_vector_type(8))) short short8;
typedef __attribute__((ext_vector_type(4))) float f32x4;

struct alignas(8) bh4 { bf16 x, y, z, w; };

static __device__ __forceinline__ float b2f(bf16 h) { return __bfloat162float(h); }

// fast tanh: 1 - 2/(exp(2v)+1); saturates correctly via inf/0
static __device__ __forceinline__ float fast_tanh(float v) {
  float e = __expf(2.0f * v);
  return 1.0f - 2.0f * __builtin_amdgcn_rcpf(e + 1.0f);
}

// ---------------- fp32 -> bf16 conversion (x input) ------------------------
__global__ __launch_bounds__(256) void f2b_kernel(const float* __restrict__ s,
                                                  bf16* __restrict__ d, long n) {
  long i = ((long)blockIdx.x * 256 + threadIdx.x) * 4;
  if (i >= n) return;
  float4 v = *(const float4*)(s + i);
  bh4 o;
  o.x = __float2bfloat16(v.x); o.y = __float2bfloat16(v.y);
  o.z = __float2bfloat16(v.z); o.w = __float2bfloat16(v.w);
  *(bh4*)(d + i) = o;
}

// 3 x [1024,1024] fp32->bf16 in one launch
struct Ptrs3 { const float* s[3]; bf16* d[3]; };
__global__ __launch_bounds__(256) void f2b3_kernel(Ptrs3 p) {
  const int which = blockIdx.x >> 10;
  long i = ((long)(blockIdx.x & 1023) * 256 + threadIdx.x) * 4;
  float4 v = *(const float4*)(p.s[which] + i);
  bh4 o;
  o.x = __float2bfloat16(v.x); o.y = __float2bfloat16(v.y);
  o.z = __float2bfloat16(v.z); o.w = __float2bfloat16(v.w);
  *(bh4*)(p.d[which] + i) = o;
}

// ---------------- fp32 [1024,1024] -> transposed bf16 (2 mats) -------------
__global__ __launch_bounds__(256) void f2bT_kernel(const float* __restrict__ s0,
                                                   const float* __restrict__ s1,
                                                   bf16* __restrict__ d0,
                                                   bf16* __restrict__ d1) {
  const float* src = blockIdx.z ? s1 : s0;
  bf16* dst = blockIdx.z ? d1 : d0;
  __shared__ bf16 tile[64][68];
  const int t = threadIdx.x;
  const int tr = t >> 4;          // 0..15
  const int tc = (t & 15) * 4;    // 0..60
  const int r0 = blockIdx.y * 64, c0 = blockIdx.x * 64;
#pragma unroll
  for (int i = 0; i < 4; ++i) {
    float4 v = *(const float4*)(src + (long)(r0 + tr + i * 16) * 1024 + c0 + tc);
    tile[tr + i * 16][tc + 0] = __float2bfloat16(v.x);
    tile[tr + i * 16][tc + 1] = __float2bfloat16(v.y);
    tile[tr + i * 16][tc + 2] = __float2bfloat16(v.z);
    tile[tr + i * 16][tc + 3] = __float2bfloat16(v.w);
  }
  __syncthreads();
#pragma unroll
  for (int i = 0; i < 4; ++i) {
    const int c = tr + i * 16;
    bh4 o;
    o.x = tile[tc + 0][c]; o.y = tile[tc + 1][c];
    o.z = tile[tc + 2][c]; o.w = tile[tc + 3][c];
    *(bh4*)(dst + (long)(c0 + c) * 1024 + r0 + tc) = o;  // dst[C][R] = src[R][C]
  }
}

// ---------------- Wo fold: WOB = bf16(g*Wo); C1=sum(g*Wo); C2=sum(b*Wo)+bo -
__global__ __launch_bounds__(256)
void wofold_kernel(const float* __restrict__ Wo, const float* __restrict__ g,
                   const float* __restrict__ b, const float* __restrict__ bo,
                   const float* __restrict__ bv, bf16* __restrict__ WOB,
                   float* __restrict__ C1, float* __restrict__ C2,
                   float* __restrict__ BBIG) {
  const int n = blockIdx.x;
  const int tid = threadIdx.x;
  float4 w = *(const float4*)(Wo + (long)n * 1024 + tid * 4);
  float4 gg = *(const float4*)(g + tid * 4);
  float4 bb = *(const float4*)(b + tid * 4);
  bf16 fw0 = __float2bfloat16(w.x * gg.x), fw1 = __float2bfloat16(w.y * gg.y);
  bf16 fw2 = __float2bfloat16(w.z * gg.z), fw3 = __float2bfloat16(w.w * gg.w);
  bh4 o; o.x = fw0; o.y = fw1; o.z = fw2; o.w = fw3;
  *(bh4*)(WOB + (long)n * 1024 + tid * 4) = o;
  float c1 = b2f(fw0) + b2f(fw1) + b2f(fw2) + b2f(fw3);
  float c2 = w.x * bb.x + w.y * bb.y + w.z * bb.z + w.w * bb.w;
#pragma unroll
  for (int off = 32; off > 0; off >>= 1) {
    c1 += __shfl_down(c1, off, 64);
    c2 += __shfl_down(c2, off, 64);
  }
  __shared__ float r1[4], r2[4];
  if ((tid & 63) == 0) { r1[tid >> 6] = c1; r2[tid >> 6] = c2; }
  __syncthreads();
  if (tid == 0) {
    C1[n] = r1[0] + r1[1] + r1[2] + r1[3];
    C2[n] = r2[0] + r2[1] + r2[2] + r2[3] + bo[n];
    BBIG[n] = bv[n];
  }
}

// BBIG[1024+b] = dot(Wsel[e,:], bsel) + bpsel[e], b in [0,2048)
__global__ __launch_bounds__(256)
void biasdot_kernel(const float* __restrict__ Wkp, const float* __restrict__ bk,
                    const float* __restrict__ bkp, const float* __restrict__ Wqp,
                    const float* __restrict__ bq, const float* __restrict__ bqp,
                    float* __restrict__ BBIG) {
  const int b = blockIdx.x;
  const int half = b >> 10, e = b & 1023;
  const float* Wrow = (half ? Wqp : Wkp) + (long)e * 1024;
  const float* bsrc = half ? bq : bk;
  const int tid = threadIdx.x;
  float4 w = *(const float4*)(Wrow + tid * 4);
  float4 bb = *(const float4*)(bsrc + tid * 4);
  float p = w.x * bb.x + w.y * bb.y + w.z * bb.z + w.w * bb.w;
#pragma unroll
  for (int off = 32; off > 0; off >>= 1) p += __shfl_down(p, off, 64);
  __shared__ float rs[4];
  if ((tid & 63) == 0) rs[tid >> 6] = p;
  __syncthreads();
  if (tid == 0)
    BBIG[1024 + b] = rs[0] + rs[1] + rs[2] + rs[3] + (half ? bqp : bkp)[e];
}

// ---------------- bf16 GEMM, C[M,N] = A[M,K] @ W[N,K]^T (+ epilogue) -------
// MODE 0 (prep): no bias, bf16 out; rows >= 1024 switch W to second matrix.
// MODE 1 (main): bf16 out = acc + bias[col], fast_tanh if col0 >= 1024.
// LDS XOR swizzle: slot (row, g) holds global col-group g^(row&7) so that
// fragment ds_read_b128 lands 2-way-per-bank (free) instead of 16-way.
#define TILE 128
#define BK 64

template <int MODE, int NXB>
__global__ __launch_bounds__(256)
void gemm_bt(const bf16* __restrict__ A, const bf16* __restrict__ W,
             const float* __restrict__ bias, void* __restrict__ Out,
             long lda, long ldc, int K) {
  __shared__ bf16 sA[TILE * BK];
  __shared__ bf16 sB[TILE * BK];

  const int id = blockIdx.x;
  const int xcd = id & 7;
  const int loc = id >> 3;
  const int bx = xcd * NXB + loc % NXB;
  const int by = loc / NXB;

  const int tid = threadIdx.x;
  const long row0 = (long)by * TILE;
  const long col0 = (long)bx * TILE;

  if (MODE == 0 && row0 >= 1024) W += 1024L * K;

  const int wave = tid >> 6;
  const int lane = tid & 63;
  const int wm = wave >> 1, wn = wave & 1;
  const int fr = lane & 15, quad = lane >> 4;
  const int sw = fr & 7;            // read-side XOR swizzle key

  f32x4 acc[4][4];
#pragma unroll
  for (int i = 0; i < 4; ++i)
#pragma unroll
    for (int j = 0; j < 4; ++j) acc[i][j] = (f32x4)0.0f;

  const int urow = tid >> 3;                      // + r*32 per staging round
  const int gcolg = (tid & 7) ^ (urow & 7);       // swizzled global col group
  const int ucol = gcolg * 8;

  for (int k0 = 0; k0 < K; k0 += BK) {
#pragma unroll
    for (int r = 0; r < 4; ++r) {
      const int rr = r * 32 + urow;
      const bf16* ga = A + (row0 + rr) * lda + k0 + ucol;
      const bf16* gb = W + (col0 + rr) * (long)K + k0 + ucol;
      bf16* la = &sA[(r * 256 + (wave << 6)) * 8];
      bf16* lb = &sB[(r * 256 + (wave << 6)) * 8];
      __builtin_amdgcn_global_load_lds((const __attribute__((address_space(1))) void*)ga,
                                       (__attribute__((address_space(3))) void*)la, 16, 0, 0);
      __builtin_amdgcn_global_load_lds((const __attribute__((address_space(1))) void*)gb,
                                       (__attribute__((address_space(3))) void*)lb, 16, 0, 0);
    }
    __syncthreads();

#pragma unroll
    for (int kk = 0; kk < BK; kk += 32) {
      const int kg = kk >> 3;
      short8 af[4], bfv[4];
#pragma unroll
      for (int i = 0; i < 4; ++i)
        af[i] = *(const short8*)&sA[(wm * 64 + i * 16 + fr) * BK + (((kg + quad) ^ sw) << 3)];
#pragma unroll
      for (int j = 0; j < 4; ++j)
        bfv[j] = *(const short8*)&sB[(wn * 64 + j * 16 + fr) * BK + (((kg + quad) ^ sw) << 3)];
#pragma unroll
      for (int i = 0; i < 4; ++i)
#pragma unroll
        for (int j = 0; j < 4; ++j)
          acc[i][j] = __builtin_amdgcn_mfma_f32_16x16x32_bf16(af[i], bfv[j], acc[i][j], 0, 0, 0);
    }
    __syncthreads();
  }

  const bool do_tanh = (MODE == 1) && (col0 >= 1024);
  // C/D layout: col = lane&15, row = quad*4 + reg (m89/m91 verified)
#pragma unroll
  for (int i = 0; i < 4; ++i) {
    const long rb = row0 + wm * 64 + i * 16 + quad * 4;
#pragma unroll
    for (int j = 0; j < 4; ++j) {
      const int col = (int)col0 + wn * 64 + j * 16 + fr;
      const float bc = (MODE == 0) ? 0.0f : bias[col];
#pragma unroll
      for (int reg = 0; reg < 4; ++reg) {
        const long r = rb + reg;
        float v = acc[i][j][reg] + bc;
        if (MODE == 1 && do_tanh) v = fast_tanh(v);
        ((bf16*)Out)[r * ldc + col] = __float2bfloat16(v);
      }
    }
  }
}

// ---------------- mega: chunk scan + LN(folded) + output GEMM --------------
// One block per 64-token chunk (256 blocks = 1/CU).
// Phase S: serial cumsum+retrieve, raw ret -> 128KB LDS A-tile (XOR-swizzled
// groups: slot g holds group g^(token&7)), LN stats via shuffle reduce.
// Phase G: out[64,1024] = rstd*(ret@WOB^T - mu*C1) + C2 + x, with WOB
// streamed through a 16KB LDS tile, register-prefetch double-buffered.
__global__ __launch_bounds__(256)
void scan_gemm_kernel(const bf16* __restrict__ PHS,   // [16384,3072]
                      const float* __restrict__ phase_scale,
                      const bf16* __restrict__ WOB,   // [1024,1024] g-folded
                      const float* __restrict__ C1,
                      const float* __restrict__ C2,
                      const float* __restrict__ xres, // fp32 residual
                      float* __restrict__ out) {
  __shared__ bf16 sret[64 * 1024];   // 128 KB
  __shared__ bf16 sB[128 * 64];      // 16 KB
  __shared__ float psum[64 * 4], psq[64 * 4];
  __shared__ float smu[64], srstd[64];

  const int tid = threadIdx.x;
  const long t0 = (long)blockIdx.x * 64;
  const int d = tid * 4;
  const int wid = tid >> 6, lane = tid & 63;

  const float inv2pi = 0.15915494309189535f;
  float4 ps = *(const float4*)(phase_scale + d);
  float psr[4] = {ps.x * inv2pi, ps.y * inv2pi, ps.z * inv2pi, ps.w * inv2pi};

  float ar[4] = {0.f, 0.f, 0.f, 0.f}, ai[4] = {0.f, 0.f, 0.f, 0.f};

  const int g0 = tid >> 1;          // feature group (of 8)
  const int sub = (tid & 1) * 4;    // offset within group

  // software-pipelined loads: fetch token s+1 while computing s
  const bf16* r0p = PHS + t0 * 3072;
  bh4 cv = *(const bh4*)(r0p + d);
  bh4 ctk = *(const bh4*)(r0p + 1024 + d);
  bh4 ctq = *(const bh4*)(r0p + 2048 + d);

  for (int s = 0; s < 64; ++s) {
    bh4 nv, ntk, ntq;
    if (s < 63) {
      const bf16* nr = PHS + (t0 + s + 1) * 3072;
      nv = *(const bh4*)(nr + d);
      ntk = *(const bh4*)(nr + 1024 + d);
      ntq = *(const bh4*)(nr + 2048 + d);
    }
    float vv[4] = {b2f(cv.x), b2f(cv.y), b2f(cv.z), b2f(cv.w)};
    float tk[4] = {b2f(ctk.x), b2f(ctk.y), b2f(ctk.z), b2f(ctk.w)};
    float tq[4] = {b2f(ctq.x), b2f(ctq.y), b2f(ctq.z), b2f(ctq.w)};
    float ret[4];
    float lsum = 0.f, lsq = 0.f;
#pragma unroll
    for (int j = 0; j < 4; ++j) {
      float rk = tk[j] * psr[j];   // revolutions
      float rq = tq[j] * psr[j];
      float ck = __builtin_amdgcn_cosf(rk);
      float sk = __builtin_amdgcn_sinf(rk);
      float cq = __builtin_amdgcn_cosf(rq);
      float sq = __builtin_amdgcn_sinf(rq);
      ar[j] += vv[j] * ck;
      ai[j] += vv[j] * sk;
      ret[j] = (ar[j] * cq + ai[j] * sq) * 0.03125f;  // / sqrt(1024)
      lsum += ret[j];
      lsq += ret[j] * ret[j];
    }
    bh4 o;
    o.x = __float2bfloat16(ret[0]); o.y = __float2bfloat16(ret[1]);
    o.z = __float2bfloat16(ret[2]); o.w = __float2bfloat16(ret[3]);
    *(bh4*)&sret[s * 1024 + (((g0 ^ (s & 7)) << 3) + sub)] = o;
#pragma unroll
    for (int off = 32; off > 0; off >>= 1) {
      lsum += __shfl_down(lsum, off, 64);
      lsq  += __shfl_down(lsq, off, 64);
    }
    if (lane == 0) { psum[s * 4 + wid] = lsum; psq[s * 4 + wid] = lsq; }
    cv = nv; ctk = ntk; ctq = ntq;
  }
  __syncthreads();
  if (tid < 64) {
    float sum = psum[tid * 4] + psum[tid * 4 + 1] + psum[tid * 4 + 2] + psum[tid * 4 + 3];
    float sq2 = psq[tid * 4] + psq[tid * 4 + 1] + psq[tid * 4 + 2] + psq[tid * 4 + 3];
    float mu = sum * (1.0f / 1024.0f);
    float var = sq2 * (1.0f / 1024.0f) - mu * mu;
    smu[tid] = mu;
    srstd[tid] = rsqrtf(var + 1e-5f);
  }
  __syncthreads();

  // ---- phase G ----
  const int wave = tid >> 6;
  const int wm = wave >> 1, wn = wave & 1;
  const int fr = lane & 15, quad = lane >> 4;
  const int sw = fr & 7;
  const int urow = tid >> 3;
  const int gcolg = (tid & 7) ^ (urow & 7);

  f32x4 acc[2][4];
  int4 pref[4];
  // preload tile 0 (n0=0, k0=0)
#pragma unroll
  for (int r = 0; r < 4; ++r)
    pref[r] = *(const int4*)(WOB + (long)(r * 32 + urow) * 1024 + gcolg * 8);

  for (int tile = 0; tile < 128; ++tile) {
    const int n0 = (tile >> 4) << 7;
    const int k0 = (tile & 15) << 6;
    __syncthreads();   // prior compute done before overwriting sB
#pragma unroll
    for (int r = 0; r < 4; ++r)
      *(int4*)&sB[(r * 256 + tid) * 8] = pref[r];
    if (tile < 127) {
      const int nt = tile + 1;
      const int nn0 = (nt >> 4) << 7, nk0 = (nt & 15) << 6;
#pragma unroll
      for (int r = 0; r < 4; ++r)
        pref[r] = *(const int4*)(WOB + (long)(nn0 + r * 32 + urow) * 1024 + nk0 + gcolg * 8);
    }
    if ((tile & 15) == 0) {
#pragma unroll
      for (int i = 0; i < 2; ++i)
#pragma unroll
        for (int j = 0; j < 4; ++j) acc[i][j] = (f32x4)0.0f;
    }
    __syncthreads();

#pragma unroll
    for (int kk = 0; kk < 64; kk += 32) {
      const int kg = kk >> 3;
      const int Gk = (k0 >> 3) + kg;   // global k-group base (+quad per lane)
      short8 af[2], bfv[4];
#pragma unroll
      for (int i = 0; i < 2; ++i)
        af[i] = *(const short8*)&sret[(wm * 32 + i * 16 + fr) * 1024 +
                                      (((Gk + quad) ^ sw) << 3)];
#pragma unroll
      for (int j = 0; j < 4; ++j)
        bfv[j] = *(const short8*)&sB[(wn * 64 + j * 16 + fr) * 64 +
                                     (((kg + quad) ^ sw) << 3)];
#pragma unroll
      for (int i = 0; i < 2; ++i)
#pragma unroll
        for (int j = 0; j < 4; ++j)
          acc[i][j] = __builtin_amdgcn_mfma_f32_16x16x32_bf16(af[i], bfv[j], acc[i][j], 0, 0, 0);
    }

    if ((tile & 15) == 15) {
      // epilogue for this 128-col band
#pragma unroll
      for (int i = 0; i < 2; ++i) {
        const int rb = wm * 32 + i * 16 + quad * 4;
#pragma unroll
        for (int j = 0; j < 4; ++j) {
          const int col = n0 + wn * 64 + j * 16 + fr;
          const float c1 = C1[col], c2 = C2[col];
#pragma unroll
          for (int reg = 0; reg < 4; ++reg) {
            const int r = rb + reg;
            const long gi = (t0 + r) * 1024 + col;
            out[gi] = srstd[r] * (acc[i][j][reg] - smu[r] * c1) + c2 + xres[gi];
          }
        }
      }
    }
  }
}

// ---------------------------------------------------------------------------
extern "C" void kernel_launch(void* const* d_in, const int* in_sizes, int n_in,
                              void* d_out, int out_size, void* d_ws, size_t ws_size,
                              hipStream_t stream) {
  (void)in_sizes; (void)n_in; (void)out_size; (void)ws_size;
  const float* x   = (const float*)d_in[0];
  const float* Wk  = (const float*)d_in[1];
  const float* bk  = (const float*)d_in[2];
  const float* Wv  = (const float*)d_in[3];
  const float* bv  = (const float*)d_in[4];
  const float* Wq  = (const float*)d_in[5];
  const float* bq  = (const float*)d_in[6];
  const float* Wkp = (const float*)d_in[7];
  const float* bkp = (const float*)d_in[8];
  const float* Wqp = (const float*)d_in[9];
  const float* bqp = (const float*)d_in[10];
  const float* ps  = (const float*)d_in[11];
  const float* lng = (const float*)d_in[12];
  const float* lnb = (const float*)d_in[13];
  const float* Wo  = (const float*)d_in[14];
  const float* bo  = (const float*)d_in[15];
  float* out = (float*)d_out;

  char* ws = (char*)d_ws;
  bf16*  XB   = (bf16*)(ws);                  // [16384,1024] bf16 x
  bf16*  PHS  = (bf16*)(ws + 33554432);       // [16384,3072] bf16: V | tanh_k | tanh_q
  bf16*  WBIG = (bf16*)(ws + 134217728);      // [3072,1024]: Wv | Wck | Wcq
  bf16*  WOB  = (bf16*)(ws + 140509184);      // [1024,1024] g-folded Wo
  bf16*  WPS  = (bf16*)(ws + 142606336);      // [2048,1024]: Wkp ; Wqp (bf16)
  bf16*  WTS  = (bf16*)(ws + 146800640);      // [2048,1024]: Wk^T ; Wq^T (bf16)
  float* BBIG = (float*)(ws + 150994944);     // [3072]: bv | b'k | b'q
  float* C1   = (float*)(ws + 151007232);     // [1024]
  float* C2   = (float*)(ws + 151011328);     // [1024]

  // conversions / weight prep
  f2b_kernel<<<16384, 256, 0, stream>>>(x, XB, 16777216L);
  Ptrs3 p3;
  p3.s[0] = Wv;  p3.d[0] = WBIG;
  p3.s[1] = Wkp; p3.d[1] = WPS;
  p3.s[2] = Wqp; p3.d[2] = WPS + 1048576;
  f2b3_kernel<<<3072, 256, 0, stream>>>(p3);
  f2bT_kernel<<<dim3(16, 16, 2), 256, 0, stream>>>(Wk, Wq, WTS, WTS + 1048576);
  wofold_kernel<<<1024, 256, 0, stream>>>(Wo, lng, lnb, bo, bv, WOB, C1, C2, BBIG);
  biasdot_kernel<<<2048, 256, 0, stream>>>(Wkp, bk, bkp, Wqp, bq, bqp, BBIG);

  // prep GEMM: [Wck;Wcq] = [Wkp;Wqp] @ [Wk^T;Wq^T]^T  (M=2048,N=1024,K=1024)
  gemm_bt<0, 1><<<128, 256, 0, stream>>>(WPS, WTS, nullptr, WBIG + 1048576,
                                         1024, 1024, 1024);
  // main GEMM: PHS = [x@Wv^T+bv | tanh(x@Wck^T+b'k) | tanh(x@Wcq^T+b'q)]
  gemm_bt<1, 3><<<3072, 256, 0, stream>>>(XB, WBIG, BBIG, PHS,
                                          1024, 3072, 1024);
  // mega: scan + LN(folded) + output GEMM + residual
  scan_gemm_kernel<<<256, 256, 0, stream>>>(PHS, ps, WOB, C1, C2, x, out);
}